// Round 2
// baseline (221.008 us; speedup 1.0000x reference)
//
#include <hip/hip_runtime.h>
#include <math.h>

// True clang vector types (v_pk_* codegen needs them).
typedef float vfloat4 __attribute__((ext_vector_type(4)));
typedef float vfloat2 __attribute__((ext_vector_type(2)));

#define UNROLL 8
#define NBLK 2048      // 2048 blk * 256 thr * 8 unroll * 4 floats == 16.7M exactly: one burst
#define THREADS 256

// ws layout (write-before-read each call; no init needed):
//   vfloat2 wd_part[NBLK] @0      : per-block (ssq_w, ssq_dw)      (k1 -> k2)
//   float   a_part[NBLK]  @16384  : per-block sum|new_w|           (k3 -> k4)
//   float   wsf[2]        @24576  : final_strength, forgetting_strength (k2 -> k3)

// ---- k1: ssq over cur_w AND w_chg. dw is ONLY needed for its norm (change_magnitude),
// ---- so its one-and-only read lives here, in a pure streaming reduce, not in the MLP pass.
// ---- NOTE: no min-waves forcing — 2-stream staging needs ~80 live VGPRs; a 64-cap spills.
__global__ __launch_bounds__(256) void wc_reduce2(const vfloat4* __restrict__ w,
                                                  const vfloat4* __restrict__ dw,
                                                  vfloat2* __restrict__ wd_part,
                                                  int n4) {
    int tid = blockIdx.x * blockDim.x + threadIdx.x;
    int stride = gridDim.x * blockDim.x;
    float sw0 = 0.f, sw1 = 0.f, sw2 = 0.f, sw3 = 0.f;
    float sd0 = 0.f, sd1 = 0.f, sd2 = 0.f, sd3 = 0.f;
    int i = tid;
    if (i + (UNROLL - 1) * stride < n4) {   // straight-line burst (taken by all threads at n=16.7M)
        vfloat4 a[UNROLL], b[UNROLL];
#pragma unroll
        for (int u = 0; u < UNROLL; u++) a[u] = w[i + u * stride];
#pragma unroll
        for (int u = 0; u < UNROLL; u++) b[u] = dw[i + u * stride];
#pragma unroll
        for (int u = 0; u < UNROLL; u++) {
            sw0 = fmaf(a[u].x, a[u].x, sw0);
            sw1 = fmaf(a[u].y, a[u].y, sw1);
            sw2 = fmaf(a[u].z, a[u].z, sw2);
            sw3 = fmaf(a[u].w, a[u].w, sw3);
            sd0 = fmaf(b[u].x, b[u].x, sd0);
            sd1 = fmaf(b[u].y, b[u].y, sd1);
            sd2 = fmaf(b[u].z, b[u].z, sd2);
            sd3 = fmaf(b[u].w, b[u].w, sd3);
        }
        i += UNROLL * stride;
    }
    for (; i < n4; i += stride) {           // generic tail (not executed at n=16.7M)
        vfloat4 a = w[i], b = dw[i];
        sw0 = fmaf(a.x, a.x, sw0); sw1 = fmaf(a.y, a.y, sw1);
        sw2 = fmaf(a.z, a.z, sw2); sw3 = fmaf(a.w, a.w, sw3);
        sd0 = fmaf(b.x, b.x, sd0); sd1 = fmaf(b.y, b.y, sd1);
        sd2 = fmaf(b.z, b.z, sd2); sd3 = fmaf(b.w, b.w, sd3);
    }
    float sw = (sw0 + sw1) + (sw2 + sw3);
    float sd = (sd0 + sd1) + (sd2 + sd3);
    for (int off = 32; off > 0; off >>= 1) {
        sw += __shfl_down(sw, off);
        sd += __shfl_down(sd, off);
    }
    __shared__ float lsw[4], lsd[4];
    int wave = threadIdx.x >> 6;
    int lane = threadIdx.x & 63;
    if (lane == 0) { lsw[wave] = sw; lsd[wave] = sd; }
    __syncthreads();
    if (threadIdx.x == 0) {
        vfloat2 p;
        p.x = (lsw[0] + lsw[1]) + (lsw[2] + lsw[3]);
        p.y = (lsd[0] + lsd[1]) + (lsd[2] + lsd[3]);
        wd_part[blockIdx.x] = p;            // contention-free
    }
}

// ---------------- k2: fold partials -> fs, fg, change_magnitude ----------------
__global__ __launch_bounds__(1024) void wc_scalars2(const vfloat2* __restrict__ wd_part,
                                                    float* __restrict__ wsf,
                                                    const float* __restrict__ fg_w1,
                                                    const float* __restrict__ fg_b1,
                                                    const float* __restrict__ fg_w2,
                                                    const float* __restrict__ fg_b2,
                                                    float* __restrict__ out_tail) {
    double sw = 0.0, sd = 0.0;
    for (int i = threadIdx.x; i < NBLK; i += 1024) {
        vfloat2 p = wd_part[i];
        sw += (double)p.x;
        sd += (double)p.y;
    }
    for (int off = 32; off > 0; off >>= 1) {
        sw += __shfl_down(sw, off);
        sd += __shfl_down(sd, off);
    }
    __shared__ double lsw[16], lsd[16];
    int wave = threadIdx.x >> 6;
    int lane = threadIdx.x & 63;
    if (lane == 0) { lsw[wave] = sw; lsd[wave] = sd; }
    __syncthreads();
    if (threadIdx.x == 0) {
        double tw = 0.0, td = 0.0;
        for (int k = 0; k < 16; k++) { tw += lsw[k]; td += lsd[k]; }
        float normw = sqrtf((float)tw);
        float fs = 1.0f / (1.0f + expf(-normw));
        fs = fminf(fmaxf(fs, 0.0f), 1.0f);
        const float tf = 0.01f, fr = 0.0001f;
        float acc = fg_b2[0];
        for (int j = 0; j < 8; j++) {
            float h = tf * fg_w1[2 * j + 0] + fr * fg_w1[2 * j + 1] + fg_b1[j];
            acc = fmaf(fmaxf(h, 0.0f), fg_w2[j], acc);
        }
        float fg = 1.0f / (1.0f + expf(-acc));
        wsf[0] = fs;
        wsf[1] = fg;
        out_tail[0] = fs;                    // final_strength
        out_tail[1] = sqrtf((float)td);      // change_magnitude
        out_tail[2] = fg;                    // forgetting_strength
        out_tail[4] = 0.5f;                  // weight_stability
        out_tail[5] = 0.0f;                  // memory_strength
    }
}

// ---- k3: consolidate + sum|new_w|. Reads ONLY w (L3-resident after k1), writes out.
// ---- The dw stream is gone: FETCH should drop to near zero (L3 hit), WRITE unchanged.
__global__ __launch_bounds__(256) void wc_consolidate2(const vfloat4* __restrict__ w,
                                                       vfloat4* __restrict__ outw,
                                                       const float* __restrict__ ur_w1,
                                                       const float* __restrict__ ur_b1,
                                                       const float* __restrict__ ur_w2,
                                                       const float* __restrict__ ur_b2,
                                                       const float* __restrict__ wsf,
                                                       float* __restrict__ a_part,
                                                       int n4) {
    float fs = wsf[0];
    float fg = wsf[1];
    float a0[16], hb[16], w2[16];
#pragma unroll
    for (int k = 0; k < 16; k++) {
        a0[k] = ur_w1[3 * k + 0];
        hb[k] = fmaf(fs, ur_w1[3 * k + 1], fmaf(fg, ur_w1[3 * k + 2], ur_b1[k]));
        w2[k] = ur_w2[k];
    }
    float b2 = ur_b2[0];

    int tid = blockIdx.x * blockDim.x + threadIdx.x;
    int stride = gridDim.x * blockDim.x;
    float sabs = 0.f;
    int i = tid;
    if (i + (UNROLL - 1) * stride < n4) {   // straight-line burst (taken by all threads at n=16.7M)
        vfloat4 v[UNROLL];
#pragma unroll
        for (int u = 0; u < UNROLL; u++) v[u] = w[i + u * stride];
#pragma unroll
        for (int u = 0; u < UNROLL; u++) {
            // 16-hinge MLP on element pairs: v_pk_fma / v_pk_max.
            vfloat2 x01 = {v[u].x, v[u].y}, x23 = {v[u].z, v[u].w};
            vfloat2 acc01 = {b2, b2}, acc23 = {b2, b2};
#pragma unroll
            for (int k = 0; k < 16; k++) {
                vfloat2 h01 = x01 * a0[k] + hb[k];
                vfloat2 h23 = x23 * a0[k] + hb[k];
                h01 = __builtin_elementwise_max(h01, (vfloat2)0.0f);
                h23 = __builtin_elementwise_max(h23, (vfloat2)0.0f);
                acc01 += h01 * w2[k];
                acc23 += h23 * w2[k];
            }
            float accs[4] = {acc01.x, acc01.y, acc23.x, acc23.y};
            float xs[4] = {v[u].x, v[u].y, v[u].z, v[u].w};
            vfloat4 o;
#pragma unroll
            for (int e = 0; e < 4; e++) {
                float t = __expf(2.0f * accs[e]);
                float th = fmaf(-2.0f, __builtin_amdgcn_rcpf(t + 1.0f), 1.0f);
                float nw = fmaf(0.001f, th, xs[e]);
                nw = fminf(fmaxf(nw, -10.0f), 10.0f);
                o[e] = nw;
                sabs += fabsf(nw);
            }
            outw[i + u * stride] = o;       // plain cacheable store: let L2/L3 defer
        }
        i += UNROLL * stride;
    }
    for (; i < n4; i += stride) {           // generic tail (not executed at n=16.7M)
        vfloat4 v = w[i];
        vfloat4 o;
#pragma unroll
        for (int e = 0; e < 4; e++) {
            float x = v[e];
            float acc = b2;
#pragma unroll
            for (int k = 0; k < 16; k++) {
                float h = fmaf(x, a0[k], hb[k]);
                acc = fmaf(fmaxf(h, 0.0f), w2[k], acc);
            }
            float t = __expf(2.0f * acc);
            float th = fmaf(-2.0f, __builtin_amdgcn_rcpf(t + 1.0f), 1.0f);
            float nw = fmaf(0.001f, th, x);
            nw = fminf(fmaxf(nw, -10.0f), 10.0f);
            o[e] = nw;
            sabs += fabsf(nw);
        }
        outw[i] = o;
    }
    for (int off = 32; off > 0; off >>= 1) sabs += __shfl_down(sabs, off);
    __shared__ float lsa[4];
    int wave = threadIdx.x >> 6;
    int lane = threadIdx.x & 63;
    if (lane == 0) lsa[wave] = sabs;
    __syncthreads();
    if (threadIdx.x == 0)
        a_part[blockIdx.x] = (lsa[0] + lsa[1]) + (lsa[2] + lsa[3]);   // no atomics
}

// ---------------- k4: fold |new_w| partials -> consolidation_quality ----------------
__global__ __launch_bounds__(1024) void wc_finalize2(const float* __restrict__ a_part,
                                                     float* __restrict__ out_tail,
                                                     double inv_n) {
    double sa = 0.0;
    for (int i = threadIdx.x; i < NBLK; i += 1024) sa += (double)a_part[i];
    for (int off = 32; off > 0; off >>= 1) sa += __shfl_down(sa, off);
    __shared__ double lsa[16];
    int wave = threadIdx.x >> 6;
    int lane = threadIdx.x & 63;
    if (lane == 0) lsa[wave] = sa;
    __syncthreads();
    if (threadIdx.x == 0) {
        double ta = 0.0;
        for (int k = 0; k < 16; k++) ta += lsa[k];
        float mean_abs = (float)(ta * inv_n);
        float dq = (mean_abs > 0.1f && mean_abs < 0.9f) ? 1.0f : mean_abs;
        out_tail[3] = (0.5f + dq) * 0.5f;    // consolidation_quality
    }
}

extern "C" void kernel_launch(void* const* d_in, const int* in_sizes, int n_in,
                              void* d_out, int out_size, void* d_ws, size_t ws_size,
                              hipStream_t stream) {
    const float* cur_w = (const float*)d_in[0];
    const float* w_chg = (const float*)d_in[1];
    const float* ur_w1 = (const float*)d_in[2];
    const float* ur_b1 = (const float*)d_in[3];
    const float* ur_w2 = (const float*)d_in[4];
    const float* ur_b2 = (const float*)d_in[5];
    const float* fg_w1 = (const float*)d_in[6];
    const float* fg_b1 = (const float*)d_in[7];
    const float* fg_w2 = (const float*)d_in[8];
    const float* fg_b2 = (const float*)d_in[9];

    int n = in_sizes[0];          // 16777216 (4096x4096)
    int n4 = n / 4;

    vfloat2* wd_part = (vfloat2*)d_ws;
    float* a_part = (float*)((char*)d_ws + 16384);
    float* wsf = (float*)((char*)d_ws + 24576);

    float* out_w = (float*)d_out;
    float* out_tail = out_w + n;

    // k1: the only read of w_chg lives here (its norm is all the pipeline needs).
    wc_reduce2<<<NBLK, THREADS, 0, stream>>>((const vfloat4*)cur_w, (const vfloat4*)w_chg,
                                             wd_part, n4);

    wc_scalars2<<<1, 1024, 0, stream>>>(wd_part, wsf, fg_w1, fg_b1, fg_w2, fg_b2, out_tail);

    // k3: w comes back out of Infinity Cache; HBM sees essentially only the out-write.
    wc_consolidate2<<<NBLK, THREADS, 0, stream>>>((const vfloat4*)cur_w, (vfloat4*)out_w,
                                                  ur_w1, ur_b1, ur_w2, ur_b2, wsf, a_part, n4);

    wc_finalize2<<<1, 1024, 0, stream>>>(a_part, out_tail, 1.0 / (double)n);
}

// Round 5
// 207.542 us; speedup vs baseline: 1.0649x; 1.0649x over previous
//
#include <hip/hip_runtime.h>
#include <math.h>

// True clang vector types (v_pk_* codegen needs them).
typedef float vfloat4 __attribute__((ext_vector_type(4)));
typedef float vfloat2 __attribute__((ext_vector_type(2)));

#define UNROLL 8
#define NBLK1 512      // pass1: grid-stride, 4 bursts per thread (resident waves)
#define NBLK 2048      // pass2: 2048 blk * 256 thr * 8 unroll * 4 floats == 16.7M, one burst
#define THREADS 256

// ws layout (ALL cross-block dataflow crosses kernel boundaries — the only publication
// mechanism that has passed on this hardware. R3/R4 lesson: same-kernel last-block
// ticket folds lose partials across XCDs under BOTH __threadfence+plain and
// __hip_atomic AGENT publication. No tickets, no atomics.):
//   float w_part[NBLK1]  @0     : ssq_w partials      (pass1 -> pass2 prologue fold)
//   float sa_part[NBLK]  @8192  : sum|new_w| partials (pass2 -> pass3)
//   float sd_part[NBLK]  @16384 : ssq_dw partials     (pass2 -> pass3)

// ---- pass1: ssq over cur_w. Grid-stride with 512 resident blocks x 4 bursts:
// ---- R2 measured the 2048-one-shot-block shape at 2.2 TB/s (latency/dispatch-bound,
// ---- VALUBusy 2.4%); resident looping amortizes per-block setup/drain (G11 shape).
__global__ __launch_bounds__(256) void wc_pass1(const vfloat4* __restrict__ w,
                                                float* __restrict__ w_part,
                                                int n4) {
    int tid = blockIdx.x * blockDim.x + threadIdx.x;
    int stride = gridDim.x * blockDim.x;     // 131072 vfloat4 at NBLK1=512
    float s0 = 0.f, s1 = 0.f, s2 = 0.f, s3 = 0.f;
    int i = tid;
    for (; i + (UNROLL - 1) * stride < n4; i += UNROLL * stride) {   // 4 bursts exactly
        vfloat4 a[UNROLL];
#pragma unroll
        for (int u = 0; u < UNROLL; u++) a[u] = w[i + u * stride];
#pragma unroll
        for (int u = 0; u < UNROLL; u++) {
            s0 = fmaf(a[u].x, a[u].x, s0);
            s1 = fmaf(a[u].y, a[u].y, s1);
            s2 = fmaf(a[u].z, a[u].z, s2);
            s3 = fmaf(a[u].w, a[u].w, s3);
        }
    }
    for (; i < n4; i += stride) {            // generic tail (not executed at n=16.7M)
        vfloat4 a = w[i];
        s0 = fmaf(a.x, a.x, s0); s1 = fmaf(a.y, a.y, s1);
        s2 = fmaf(a.z, a.z, s2); s3 = fmaf(a.w, a.w, s3);
    }
    float sw = (s0 + s1) + (s2 + s3);
    for (int off = 32; off > 0; off >>= 1) sw += __shfl_down(sw, off);
    __shared__ float ls[4];
    int wave = threadIdx.x >> 6;
    int lane = threadIdx.x & 63;
    if (lane == 0) ls[wave] = sw;
    __syncthreads();
    if (threadIdx.x == 0)
        w_part[blockIdx.x] = (ls[0] + ls[1]) + (ls[2] + ls[3]);  // kernel-boundary handoff
}

// ---- pass2: prologue = every block redundantly folds w_part (512 floats, L2-broadcast,
// ---- 2 loads/thread) -> fs,fg. Main loop = R0's proven fat MLP pass (4.4 TB/s eff).
// ---- Epilogue = plain-store partials; the fold happens in pass3 across the boundary.
__global__ __launch_bounds__(256) void wc_pass2(const vfloat4* __restrict__ w,
                                                const vfloat4* __restrict__ dw,
                                                vfloat4* __restrict__ outw,
                                                const float* __restrict__ ur_w1,
                                                const float* __restrict__ ur_b1,
                                                const float* __restrict__ ur_w2,
                                                const float* __restrict__ ur_b2,
                                                const float* __restrict__ fg_w1,
                                                const float* __restrict__ fg_b1,
                                                const float* __restrict__ fg_w2,
                                                const float* __restrict__ fg_b2,
                                                const float* __restrict__ w_part,
                                                float* __restrict__ sa_part,
                                                float* __restrict__ sd_part,
                                                float* __restrict__ out_tail,
                                                int n4) {
    int wave = threadIdx.x >> 6;
    int lane = threadIdx.x & 63;

    // ---------- prologue: fs, fg (inputs crossed the pass1->pass2 kernel boundary) ----------
    double pw = 0.0;
    for (int k = threadIdx.x; k < NBLK1; k += THREADS) pw += (double)w_part[k];
    for (int off = 32; off > 0; off >>= 1) pw += __shfl_down(pw, off);
    __shared__ double lspw[4];
    __shared__ float s_fs, s_fg;
    if (lane == 0) lspw[wave] = pw;
    __syncthreads();
    if (threadIdx.x == 0) {
        double tw = (lspw[0] + lspw[1]) + (lspw[2] + lspw[3]);
        float normw = sqrtf((float)tw);
        float fsv = 1.0f / (1.0f + expf(-normw));
        fsv = fminf(fmaxf(fsv, 0.0f), 1.0f);
        const float tf = 0.01f, fr = 0.0001f;
        float acc = fg_b2[0];
        for (int j = 0; j < 8; j++) {
            float h = tf * fg_w1[2 * j + 0] + fr * fg_w1[2 * j + 1] + fg_b1[j];
            acc = fmaf(fmaxf(h, 0.0f), fg_w2[j], acc);
        }
        s_fs = fsv;
        s_fg = 1.0f / (1.0f + expf(-acc));
        if (blockIdx.x == 0) {               // one block writes the scalar outputs
            out_tail[0] = fsv;               // final_strength
            out_tail[2] = s_fg;              // forgetting_strength
            out_tail[4] = 0.5f;              // weight_stability
            out_tail[5] = 0.0f;              // memory_strength
        }
    }
    __syncthreads();
    float fs = s_fs;
    float fg = s_fg;

    // ---------- coefficient prep ----------
    float a0[16], hb[16], w2[16];
#pragma unroll
    for (int k = 0; k < 16; k++) {
        a0[k] = ur_w1[3 * k + 0];
        hb[k] = fmaf(fs, ur_w1[3 * k + 1], fmaf(fg, ur_w1[3 * k + 2], ur_b1[k]));
        w2[k] = ur_w2[k];
    }
    float b2 = ur_b2[0];

    // ---------- main loop (R0's proven 44 µs shape) ----------
    int tid = blockIdx.x * blockDim.x + threadIdx.x;
    int stride = gridDim.x * blockDim.x;
    float sabs = 0.f;
    vfloat2 sdv01 = {0.f, 0.f}, sdv23 = {0.f, 0.f};
    int i = tid;
    if (i + (UNROLL - 1) * stride < n4) {   // straight-line burst (all threads at n=16.7M)
        vfloat4 v[UNROLL], d[UNROLL];
#pragma unroll
        for (int u = 0; u < UNROLL; u++) v[u] = w[i + u * stride];
#pragma unroll
        for (int u = 0; u < UNROLL; u++) d[u] = dw[i + u * stride];
#pragma unroll
        for (int u = 0; u < UNROLL; u++) {
            // ssq_dw, packed (v_pk_fma_f32)
            vfloat2 d01 = {d[u].x, d[u].y}, d23 = {d[u].z, d[u].w};
            sdv01 += d01 * d01;
            sdv23 += d23 * d23;
            // 16-hinge MLP on element pairs: v_pk_fma / v_pk_max.
            vfloat2 x01 = {v[u].x, v[u].y}, x23 = {v[u].z, v[u].w};
            vfloat2 acc01 = {b2, b2}, acc23 = {b2, b2};
#pragma unroll
            for (int k = 0; k < 16; k++) {
                vfloat2 h01 = x01 * a0[k] + hb[k];
                vfloat2 h23 = x23 * a0[k] + hb[k];
                h01 = __builtin_elementwise_max(h01, (vfloat2)0.0f);
                h23 = __builtin_elementwise_max(h23, (vfloat2)0.0f);
                acc01 += h01 * w2[k];
                acc23 += h23 * w2[k];
            }
            float accs[4] = {acc01.x, acc01.y, acc23.x, acc23.y};
            float xs[4] = {v[u].x, v[u].y, v[u].z, v[u].w};
            vfloat4 o;
#pragma unroll
            for (int e = 0; e < 4; e++) {
                float t = __expf(2.0f * accs[e]);
                float th = fmaf(-2.0f, __builtin_amdgcn_rcpf(t + 1.0f), 1.0f);
                float nw = fmaf(0.001f, th, xs[e]);
                nw = fminf(fmaxf(nw, -10.0f), 10.0f);
                o[e] = nw;
                sabs += fabsf(nw);
            }
            outw[i + u * stride] = o;       // plain cacheable store: let L2/L3 defer
        }
        i += UNROLL * stride;
    }
    for (; i < n4; i += stride) {           // generic tail (not executed at n=16.7M)
        vfloat4 v = w[i];
        vfloat4 d = dw[i];
        vfloat2 d01 = {d.x, d.y}, d23 = {d.z, d.w};
        sdv01 += d01 * d01;
        sdv23 += d23 * d23;
        vfloat4 o;
#pragma unroll
        for (int e = 0; e < 4; e++) {
            float x = v[e];
            float acc = b2;
#pragma unroll
            for (int k = 0; k < 16; k++) {
                float h = fmaf(x, a0[k], hb[k]);
                acc = fmaf(fmaxf(h, 0.0f), w2[k], acc);
            }
            float t = __expf(2.0f * acc);
            float th = fmaf(-2.0f, __builtin_amdgcn_rcpf(t + 1.0f), 1.0f);
            float nw = fmaf(0.001f, th, x);
            nw = fminf(fmaxf(nw, -10.0f), 10.0f);
            o[e] = nw;
            sabs += fabsf(nw);
        }
        outw[i] = o;
    }

    // ---------- epilogue: block reduce, plain-store partials (read in pass3) ----------
    float sdw = (sdv01.x + sdv01.y) + (sdv23.x + sdv23.y);
    for (int off = 32; off > 0; off >>= 1) {
        sabs += __shfl_down(sabs, off);
        sdw  += __shfl_down(sdw, off);
    }
    __shared__ float lsa[4], lsd[4];
    if (lane == 0) { lsa[wave] = sabs; lsd[wave] = sdw; }
    __syncthreads();
    if (threadIdx.x == 0) {
        sa_part[blockIdx.x] = (lsa[0] + lsa[1]) + (lsa[2] + lsa[3]);
        sd_part[blockIdx.x] = (lsd[0] + lsd[1]) + (lsd[2] + lsd[3]);
    }
}

// ---- pass3: 1-block fold of pass2's partials -> change_magnitude, quality ----
__global__ __launch_bounds__(1024) void wc_pass3(const float* __restrict__ sa_part,
                                                 const float* __restrict__ sd_part,
                                                 float* __restrict__ out_tail,
                                                 double inv_n) {
    double sa = 0.0, sd = 0.0;
    for (int i = threadIdx.x; i < NBLK; i += 1024) {
        sa += (double)sa_part[i];
        sd += (double)sd_part[i];
    }
    for (int off = 32; off > 0; off >>= 1) {
        sa += __shfl_down(sa, off);
        sd += __shfl_down(sd, off);
    }
    __shared__ double lsa[16], lsd[16];
    int wave = threadIdx.x >> 6;
    int lane = threadIdx.x & 63;
    if (lane == 0) { lsa[wave] = sa; lsd[wave] = sd; }
    __syncthreads();
    if (threadIdx.x == 0) {
        double ta = 0.0, td = 0.0;
        for (int k = 0; k < 16; k++) { ta += lsa[k]; td += lsd[k]; }
        out_tail[1] = sqrtf((float)td);          // change_magnitude
        float mean_abs = (float)(ta * inv_n);
        float dq = (mean_abs > 0.1f && mean_abs < 0.9f) ? 1.0f : mean_abs;
        out_tail[3] = (0.5f + dq) * 0.5f;        // consolidation_quality
    }
}

extern "C" void kernel_launch(void* const* d_in, const int* in_sizes, int n_in,
                              void* d_out, int out_size, void* d_ws, size_t ws_size,
                              hipStream_t stream) {
    const float* cur_w = (const float*)d_in[0];
    const float* w_chg = (const float*)d_in[1];
    const float* ur_w1 = (const float*)d_in[2];
    const float* ur_b1 = (const float*)d_in[3];
    const float* ur_w2 = (const float*)d_in[4];
    const float* ur_b2 = (const float*)d_in[5];
    const float* fg_w1 = (const float*)d_in[6];
    const float* fg_b1 = (const float*)d_in[7];
    const float* fg_w2 = (const float*)d_in[8];
    const float* fg_b2 = (const float*)d_in[9];

    int n = in_sizes[0];          // 16777216 (4096x4096)
    int n4 = n / 4;

    float* w_part = (float*)d_ws;
    float* sa_part = (float*)((char*)d_ws + 8192);
    float* sd_part = (float*)((char*)d_ws + 16384);

    float* out_w = (float*)d_out;
    float* out_tail = out_w + n;

    wc_pass1<<<NBLK1, THREADS, 0, stream>>>((const vfloat4*)cur_w, w_part, n4);

    wc_pass2<<<NBLK, THREADS, 0, stream>>>((const vfloat4*)cur_w, (const vfloat4*)w_chg,
                                           (vfloat4*)out_w, ur_w1, ur_b1, ur_w2, ur_b2,
                                           fg_w1, fg_b1, fg_w2, fg_b2,
                                           w_part, sa_part, sd_part, out_tail, n4);

    wc_pass3<<<1, 1024, 0, stream>>>(sa_part, sd_part, out_tail, 1.0 / (double)n);
}

// Round 6
// 200.474 us; speedup vs baseline: 1.1024x; 1.0353x over previous
//
#include <hip/hip_runtime.h>
#include <math.h>

// True clang vector types (v_pk_* codegen needs them).
typedef float vfloat4 __attribute__((ext_vector_type(4)));
typedef float vfloat2 __attribute__((ext_vector_type(2)));

#define UNROLL 8
#define PBLK 128       // prefix pass: 128 blocks over 4M-element prefix
#define NBLK 2048      // pass2: 2048 blk * 256 thr * 8 unroll * 4 floats == 16.7M, one burst
#define THREADS 256

// ws layout (ALL cross-block dataflow crosses kernel boundaries — R3/R4 lesson:
// same-kernel ticket folds lose partials across XCDs; no tickets, no atomics):
//   float w_part[PBLK]   @0     : prefix ssq_w partials (pass1 -> pass2 prologue)
//   float sa_part[NBLK]  @8192  : sum|new_w| partials   (pass2 -> pass3)
//   float sd_part[NBLK]  @16384 : ssq_dw partials       (pass2 -> pass3)
//
// fs certification (exact, data-independent logic): fs = sigmoid(norm(w)); in float32
// sigmoid(x) == 1.0f for x >= 18 (expf(-18)=1.5e-8 < eps/2). ssq is monotone in any
// element subset, so prefix_ssq >= 400 (> 324 = 18^2, margin) PROVES total norm >= 18
// and fs == 1.0f bit-exactly (the reference rounds identically). If the certificate
// fails (pathological input), every pass2 block runs an identical deterministic
// full-ssq backstop — slow but correct and block-consistent.

// ---- pass1: ssq over a 4M-element PREFIX of cur_w (16 MB instead of 64 MB).
// ---- R2/R5 measured thin full reduces at 2.0-2.2 TB/s latency-bound (~30 us);
// ---- shrinking bytes 4x is worth more than chasing its issue rate.
__global__ __launch_bounds__(256) void wc_prefix(const vfloat4* __restrict__ w,
                                                 float* __restrict__ w_part,
                                                 int pn4) {
    int tid = blockIdx.x * blockDim.x + threadIdx.x;
    int stride = gridDim.x * blockDim.x;     // 32768 threads at PBLK=128
    float s0 = 0.f, s1 = 0.f, s2 = 0.f, s3 = 0.f;
    int i = tid;
    for (; i + (UNROLL - 1) * stride < pn4; i += UNROLL * stride) {  // 4 bursts at 1M vfloat4
        vfloat4 a[UNROLL];
#pragma unroll
        for (int u = 0; u < UNROLL; u++) a[u] = w[i + u * stride];
#pragma unroll
        for (int u = 0; u < UNROLL; u++) {
            s0 = fmaf(a[u].x, a[u].x, s0);
            s1 = fmaf(a[u].y, a[u].y, s1);
            s2 = fmaf(a[u].z, a[u].z, s2);
            s3 = fmaf(a[u].w, a[u].w, s3);
        }
    }
    for (; i < pn4; i += stride) {
        vfloat4 a = w[i];
        s0 = fmaf(a.x, a.x, s0); s1 = fmaf(a.y, a.y, s1);
        s2 = fmaf(a.z, a.z, s2); s3 = fmaf(a.w, a.w, s3);
    }
    float sw = (s0 + s1) + (s2 + s3);
    for (int off = 32; off > 0; off >>= 1) sw += __shfl_down(sw, off);
    __shared__ float ls[4];
    int wave = threadIdx.x >> 6;
    int lane = threadIdx.x & 63;
    if (lane == 0) ls[wave] = sw;
    __syncthreads();
    if (threadIdx.x == 0)
        w_part[blockIdx.x] = (ls[0] + ls[1]) + (ls[2] + ls[3]);  // kernel-boundary handoff
}

// ---- pass2: prologue (all-float; R5's double-precision fold perturbed regalloc and
// ---- cost 12 us of main-loop ILP) -> fs,fg. Main loop: R0's fat MLP shape, v-consumed-
// ---- before-d ordering, 128-VGPR budget via __launch_bounds__(256,4).
__global__ __launch_bounds__(256, 4) void wc_pass2(const vfloat4* __restrict__ w,
                                                   const vfloat4* __restrict__ dw,
                                                   vfloat4* __restrict__ outw,
                                                   const float* __restrict__ ur_w1,
                                                   const float* __restrict__ ur_b1,
                                                   const float* __restrict__ ur_w2,
                                                   const float* __restrict__ ur_b2,
                                                   const float* __restrict__ fg_w1,
                                                   const float* __restrict__ fg_b1,
                                                   const float* __restrict__ fg_w2,
                                                   const float* __restrict__ fg_b2,
                                                   const float* __restrict__ w_part,
                                                   float* __restrict__ sa_part,
                                                   float* __restrict__ sd_part,
                                                   float* __restrict__ out_tail,
                                                   int n4) {
    int wave = threadIdx.x >> 6;
    int lane = threadIdx.x & 63;

    // ---------- prologue: certified fs + fg (float-only) ----------
    float pv = (threadIdx.x < PBLK) ? w_part[threadIdx.x] : 0.f;
    for (int off = 32; off > 0; off >>= 1) pv += __shfl_down(pv, off);
    __shared__ float lsp[4];
    __shared__ float s_fs, s_fg, s_pref;
    if (lane == 0) lsp[wave] = pv;
    __syncthreads();
    if (threadIdx.x == 0)
        s_pref = (lsp[0] + lsp[1]) + (lsp[2] + lsp[3]);
    __syncthreads();
    float pref = s_pref;                      // block-uniform

    if (pref >= 400.0f) {                     // certificate: fs == 1.0f exactly
        if (threadIdx.x == 0) s_fs = 1.0f;
    } else {
        // Backstop: full ssq, identical deterministic sequence in EVERY block
        // (depends only on threadIdx) -> identical fs across blocks. Never taken
        // for sane inputs; correctness for pathological ones.
        float b0 = 0.f, b1 = 0.f, b2s = 0.f, b3 = 0.f;
        for (int k = threadIdx.x; k < n4; k += THREADS) {
            vfloat4 a = w[k];
            b0 = fmaf(a.x, a.x, b0); b1 = fmaf(a.y, a.y, b1);
            b2s = fmaf(a.z, a.z, b2s); b3 = fmaf(a.w, a.w, b3);
        }
        float bs = (b0 + b1) + (b2s + b3);
        for (int off = 32; off > 0; off >>= 1) bs += __shfl_down(bs, off);
        if (lane == 0) lsp[wave] = bs;
        __syncthreads();
        if (threadIdx.x == 0) {
            float tw = (lsp[0] + lsp[1]) + (lsp[2] + lsp[3]);
            float fsv = 1.0f / (1.0f + expf(-sqrtf(tw)));
            s_fs = fminf(fmaxf(fsv, 0.0f), 1.0f);
        }
    }
    if (threadIdx.x == 0) {
        const float tf = 0.01f, fr = 0.0001f;
        float acc = fg_b2[0];
        for (int j = 0; j < 8; j++) {
            float h = tf * fg_w1[2 * j + 0] + fr * fg_w1[2 * j + 1] + fg_b1[j];
            acc = fmaf(fmaxf(h, 0.0f), fg_w2[j], acc);
        }
        s_fg = 1.0f / (1.0f + expf(-acc));
    }
    __syncthreads();
    float fs = s_fs;
    float fg = s_fg;
    if (blockIdx.x == 0 && threadIdx.x == 0) {
        out_tail[0] = fs;                    // final_strength
        out_tail[2] = fg;                    // forgetting_strength
        out_tail[4] = 0.5f;                  // weight_stability
        out_tail[5] = 0.0f;                  // memory_strength
    }

    // ---------- coefficient prep ----------
    float a0[16], hb[16], w2[16];
#pragma unroll
    for (int k = 0; k < 16; k++) {
        a0[k] = ur_w1[3 * k + 0];
        hb[k] = fmaf(fs, ur_w1[3 * k + 1], fmaf(fg, ur_w1[3 * k + 2], ur_b1[k]));
        w2[k] = ur_w2[k];
    }
    float b2 = ur_b2[0];

    // ---------- main loop: one 8-burst; consume v (MLP+store) BEFORE d so the
    // ---------- d loads hide under ~400 cycles of MLP compute ----------
    int tid = blockIdx.x * blockDim.x + threadIdx.x;
    int stride = gridDim.x * blockDim.x;
    float sabs = 0.f;
    vfloat2 sdv01 = {0.f, 0.f}, sdv23 = {0.f, 0.f};
    int i = tid;
    if (i + (UNROLL - 1) * stride < n4) {   // straight-line burst (all threads at n=16.7M)
        vfloat4 v[UNROLL], d[UNROLL];
#pragma unroll
        for (int u = 0; u < UNROLL; u++) v[u] = w[i + u * stride];
#pragma unroll
        for (int u = 0; u < UNROLL; u++) d[u] = dw[i + u * stride];
#pragma unroll
        for (int u = 0; u < UNROLL; u++) {
            // 16-hinge MLP on element pairs: v_pk_fma / v_pk_max.
            vfloat2 x01 = {v[u].x, v[u].y}, x23 = {v[u].z, v[u].w};
            vfloat2 acc01 = {b2, b2}, acc23 = {b2, b2};
#pragma unroll
            for (int k = 0; k < 16; k++) {
                vfloat2 h01 = x01 * a0[k] + hb[k];
                vfloat2 h23 = x23 * a0[k] + hb[k];
                h01 = __builtin_elementwise_max(h01, (vfloat2)0.0f);
                h23 = __builtin_elementwise_max(h23, (vfloat2)0.0f);
                acc01 += h01 * w2[k];
                acc23 += h23 * w2[k];
            }
            float accs[4] = {acc01.x, acc01.y, acc23.x, acc23.y};
            float xs[4] = {v[u].x, v[u].y, v[u].z, v[u].w};
            vfloat4 o;
#pragma unroll
            for (int e = 0; e < 4; e++) {
                float t = __expf(2.0f * accs[e]);
                float th = fmaf(-2.0f, __builtin_amdgcn_rcpf(t + 1.0f), 1.0f);
                float nw = fmaf(0.001f, th, xs[e]);
                nw = fminf(fmaxf(nw, -10.0f), 10.0f);
                o[e] = nw;
                sabs += fabsf(nw);
            }
            outw[i + u * stride] = o;       // plain cacheable store: let L2/L3 defer
        }
#pragma unroll
        for (int u = 0; u < UNROLL; u++) {  // ssq_dw after all MLP work (max load cover)
            vfloat2 d01 = {d[u].x, d[u].y}, d23 = {d[u].z, d[u].w};
            sdv01 += d01 * d01;
            sdv23 += d23 * d23;
        }
        i += UNROLL * stride;
    }
    for (; i < n4; i += stride) {           // generic tail (not executed at n=16.7M)
        vfloat4 v = w[i];
        vfloat4 d = dw[i];
        vfloat2 d01 = {d.x, d.y}, d23 = {d.z, d.w};
        sdv01 += d01 * d01;
        sdv23 += d23 * d23;
        vfloat4 o;
#pragma unroll
        for (int e = 0; e < 4; e++) {
            float x = v[e];
            float acc = b2;
#pragma unroll
            for (int k = 0; k < 16; k++) {
                float h = fmaf(x, a0[k], hb[k]);
                acc = fmaf(fmaxf(h, 0.0f), w2[k], acc);
            }
            float t = __expf(2.0f * acc);
            float th = fmaf(-2.0f, __builtin_amdgcn_rcpf(t + 1.0f), 1.0f);
            float nw = fmaf(0.001f, th, x);
            nw = fminf(fmaxf(nw, -10.0f), 10.0f);
            o[e] = nw;
            sabs += fabsf(nw);
        }
        outw[i] = o;
    }

    // ---------- epilogue: block reduce, plain-store partials (read in pass3) ----------
    float sdw = (sdv01.x + sdv01.y) + (sdv23.x + sdv23.y);
    for (int off = 32; off > 0; off >>= 1) {
        sabs += __shfl_down(sabs, off);
        sdw  += __shfl_down(sdw, off);
    }
    __shared__ float lsa[4], lsd[4];
    if (lane == 0) { lsa[wave] = sabs; lsd[wave] = sdw; }
    __syncthreads();
    if (threadIdx.x == 0) {
        sa_part[blockIdx.x] = (lsa[0] + lsa[1]) + (lsa[2] + lsa[3]);
        sd_part[blockIdx.x] = (lsd[0] + lsd[1]) + (lsd[2] + lsd[3]);
    }
}

// ---- pass3: 1-block fold of pass2's partials -> change_magnitude, quality ----
__global__ __launch_bounds__(1024) void wc_pass3(const float* __restrict__ sa_part,
                                                 const float* __restrict__ sd_part,
                                                 float* __restrict__ out_tail,
                                                 double inv_n) {
    double sa = 0.0, sd = 0.0;
    for (int i = threadIdx.x; i < NBLK; i += 1024) {
        sa += (double)sa_part[i];
        sd += (double)sd_part[i];
    }
    for (int off = 32; off > 0; off >>= 1) {
        sa += __shfl_down(sa, off);
        sd += __shfl_down(sd, off);
    }
    __shared__ double lsa[16], lsd[16];
    int wave = threadIdx.x >> 6;
    int lane = threadIdx.x & 63;
    if (lane == 0) { lsa[wave] = sa; lsd[wave] = sd; }
    __syncthreads();
    if (threadIdx.x == 0) {
        double ta = 0.0, td = 0.0;
        for (int k = 0; k < 16; k++) { ta += lsa[k]; td += lsd[k]; }
        out_tail[1] = sqrtf((float)td);          // change_magnitude
        float mean_abs = (float)(ta * inv_n);
        float dq = (mean_abs > 0.1f && mean_abs < 0.9f) ? 1.0f : mean_abs;
        out_tail[3] = (0.5f + dq) * 0.5f;        // consolidation_quality
    }
}

extern "C" void kernel_launch(void* const* d_in, const int* in_sizes, int n_in,
                              void* d_out, int out_size, void* d_ws, size_t ws_size,
                              hipStream_t stream) {
    const float* cur_w = (const float*)d_in[0];
    const float* w_chg = (const float*)d_in[1];
    const float* ur_w1 = (const float*)d_in[2];
    const float* ur_b1 = (const float*)d_in[3];
    const float* ur_w2 = (const float*)d_in[4];
    const float* ur_b2 = (const float*)d_in[5];
    const float* fg_w1 = (const float*)d_in[6];
    const float* fg_b1 = (const float*)d_in[7];
    const float* fg_w2 = (const float*)d_in[8];
    const float* fg_b2 = (const float*)d_in[9];

    int n = in_sizes[0];          // 16777216 (4096x4096)
    int n4 = n / 4;

    int pn4 = n4 < (1 << 20) ? n4 : (1 << 20);   // 4M-element prefix (1M vfloat4)

    float* w_part = (float*)d_ws;
    float* sa_part = (float*)((char*)d_ws + 8192);
    float* sd_part = (float*)((char*)d_ws + 16384);

    float* out_w = (float*)d_out;
    float* out_tail = out_w + n;

    wc_prefix<<<PBLK, THREADS, 0, stream>>>((const vfloat4*)cur_w, w_part, pn4);

    wc_pass2<<<NBLK, THREADS, 0, stream>>>((const vfloat4*)cur_w, (const vfloat4*)w_chg,
                                           (vfloat4*)out_w, ur_w1, ur_b1, ur_w2, ur_b2,
                                           fg_w1, fg_b1, fg_w2, fg_b2,
                                           w_part, sa_part, sd_part, out_tail, n4);

    wc_pass3<<<1, 1024, 0, stream>>>(sa_part, sd_part, out_tail, 1.0 / (double)n);
}

// Round 7
// 199.817 us; speedup vs baseline: 1.1061x; 1.0033x over previous
//
#include <hip/hip_runtime.h>
#include <math.h>

// True clang vector types (v_pk_* codegen needs them).
typedef float vfloat4 __attribute__((ext_vector_type(4)));
typedef float vfloat2 __attribute__((ext_vector_type(2)));

#define UNROLL 8
#define PBLK 128       // prefix pass: 128 blocks over 4M-element prefix
#define NBLK 2048      // consolidate: 2048 blk * 256 thr * 8 unroll * 4 floats == 16.7M
#define THREADS 256

// ws layout (ALL cross-block dataflow crosses kernel boundaries — R3/R4 lesson:
// same-kernel ticket folds lose partials across XCDs under both __threadfence+plain
// and __hip_atomic AGENT publication. No tickets, no atomics.):
//   float   w_part[PBLK]   @0     : prefix ssq_w partials (prefix -> scalars)
//   vfloat2 cd_part[NBLK]  @8192  : (sum|new_w|, ssq_dw)  (consolidate -> finalize)
//   float   wsf[2]         @24576 : fs, fg               (scalars -> consolidate)
//
// R5/R6 lesson (measured): ANY prologue added to the fat consolidate kernel degrades
// its main-loop ILP (44 -> 56 -> 68 us; VALUBusy 43 -> 35 -> 28%). The fat kernel is
// kept VERBATIM from R0 (measured 44 us); all scalar logic lives in a tiny 1-block
// kernel whose code the fat kernel's regalloc never sees.
//
// fs certificate (exact, data-independent logic): fs = sigmoid(norm(w)); in float32
// sigmoid(x) == 1.0f for x >= 18 (expf(-18)=1.5e-8 < half-ulp of 1.0). ssq is monotone
// in any element subset, so prefix_ssq >= 400 (norm >= 20 > 18) PROVES fs == 1.0f
// bit-exactly. Pathological inputs take a slow 1-block full-ssq backstop (correct,
// never taken for sane data: E[prefix_ssq] ~ 42000).

// ---- k1: ssq over a 4M-element PREFIX of cur_w (16 MB instead of 64 MB).
// ---- R2/R5 measured thin full reduces at 2.0-2.2 TB/s latency-bound (~30 us);
// ---- shrinking bytes 4x beats chasing the issue rate. Validated in R6.
__global__ __launch_bounds__(256) void wc_prefix(const vfloat4* __restrict__ w,
                                                 float* __restrict__ w_part,
                                                 int pn4) {
    int tid = blockIdx.x * blockDim.x + threadIdx.x;
    int stride = gridDim.x * blockDim.x;     // 32768 threads at PBLK=128
    float s0 = 0.f, s1 = 0.f, s2 = 0.f, s3 = 0.f;
    int i = tid;
    for (; i + (UNROLL - 1) * stride < pn4; i += UNROLL * stride) {  // 4 bursts at 1M vfloat4
        vfloat4 a[UNROLL];
#pragma unroll
        for (int u = 0; u < UNROLL; u++) a[u] = w[i + u * stride];
#pragma unroll
        for (int u = 0; u < UNROLL; u++) {
            s0 = fmaf(a[u].x, a[u].x, s0);
            s1 = fmaf(a[u].y, a[u].y, s1);
            s2 = fmaf(a[u].z, a[u].z, s2);
            s3 = fmaf(a[u].w, a[u].w, s3);
        }
    }
    for (; i < pn4; i += stride) {
        vfloat4 a = w[i];
        s0 = fmaf(a.x, a.x, s0); s1 = fmaf(a.y, a.y, s1);
        s2 = fmaf(a.z, a.z, s2); s3 = fmaf(a.w, a.w, s3);
    }
    float sw = (s0 + s1) + (s2 + s3);
    for (int off = 32; off > 0; off >>= 1) sw += __shfl_down(sw, off);
    __shared__ float ls[4];
    int wave = threadIdx.x >> 6;
    int lane = threadIdx.x & 63;
    if (lane == 0) ls[wave] = sw;
    __syncthreads();
    if (threadIdx.x == 0)
        w_part[blockIdx.x] = (ls[0] + ls[1]) + (ls[2] + ls[3]);  // kernel-boundary handoff
}

// ---- k2: 1-block scalars. Certificate + (never-taken) backstop + fg MLP.
// ---- Quarantined here so the fat kernel's codegen is untouched by this CFG.
__global__ __launch_bounds__(256) void wc_scalars(const float* __restrict__ w_part,
                                                  const vfloat4* __restrict__ w,
                                                  float* __restrict__ wsf,
                                                  const float* __restrict__ fg_w1,
                                                  const float* __restrict__ fg_b1,
                                                  const float* __restrict__ fg_w2,
                                                  const float* __restrict__ fg_b2,
                                                  float* __restrict__ out_tail,
                                                  int n4) {
    int wave = threadIdx.x >> 6;
    int lane = threadIdx.x & 63;
    __shared__ float lsp[4];
    __shared__ float s_pref;
    float pv = (threadIdx.x < PBLK) ? w_part[threadIdx.x] : 0.f;
    for (int off = 32; off > 0; off >>= 1) pv += __shfl_down(pv, off);
    if (lane == 0) lsp[wave] = pv;
    __syncthreads();
    if (threadIdx.x == 0) s_pref = (lsp[0] + lsp[1]) + (lsp[2] + lsp[3]);
    __syncthreads();

    float fs;
    if (s_pref >= 400.0f) {
        fs = 1.0f;                            // certified exact (see header comment)
    } else {
        // Backstop: full ssq with one block. ~100x slower than a grid reduce but
        // correct; only reachable for pathological inputs.
        float b0 = 0.f, b1 = 0.f, b2s = 0.f, b3 = 0.f;
        for (int k = threadIdx.x; k < n4; k += THREADS) {
            vfloat4 a = w[k];
            b0 = fmaf(a.x, a.x, b0); b1 = fmaf(a.y, a.y, b1);
            b2s = fmaf(a.z, a.z, b2s); b3 = fmaf(a.w, a.w, b3);
        }
        float bs = (b0 + b1) + (b2s + b3);
        for (int off = 32; off > 0; off >>= 1) bs += __shfl_down(bs, off);
        __shared__ float lsb[4];
        if (lane == 0) lsb[wave] = bs;
        __syncthreads();
        float tw = (lsb[0] + lsb[1]) + (lsb[2] + lsb[3]);
        float fsv = 1.0f / (1.0f + expf(-sqrtf(tw)));
        fs = fminf(fmaxf(fsv, 0.0f), 1.0f);
    }

    if (threadIdx.x == 0) {
        const float tf = 0.01f, fr = 0.0001f;
        float acc = fg_b2[0];
        for (int j = 0; j < 8; j++) {
            float h = tf * fg_w1[2 * j + 0] + fr * fg_w1[2 * j + 1] + fg_b1[j];
            acc = fmaf(fmaxf(h, 0.0f), fg_w2[j], acc);
        }
        float fg = 1.0f / (1.0f + expf(-acc));
        wsf[0] = fs;
        wsf[1] = fg;
        out_tail[0] = fs;     // final_strength
        out_tail[2] = fg;     // forgetting_strength
        out_tail[4] = 0.5f;   // weight_stability
        out_tail[5] = 0.0f;   // memory_strength
    }
}

// ---- k3: VERBATIM R0 consolidate (measured 44 us, VALUBusy 43%, VGPR 68).
// ---- fs/fg via wsf scalar loads; ssq_dw interleaved in the u-loop (the R6
// ---- v-before-d reorder extended d[] live ranges and cost 24 us — reverted).
__global__ __launch_bounds__(256) void wc_consolidate(const vfloat4* __restrict__ w,
                                                      const vfloat4* __restrict__ dw,
                                                      vfloat4* __restrict__ outw,
                                                      const float* __restrict__ ur_w1,
                                                      const float* __restrict__ ur_b1,
                                                      const float* __restrict__ ur_w2,
                                                      const float* __restrict__ ur_b2,
                                                      const float* __restrict__ wsf,
                                                      vfloat2* __restrict__ cd_part,
                                                      int n4) {
    float fs = wsf[0];
    float fg = wsf[1];
    float a0[16], hb[16], w2[16];
#pragma unroll
    for (int k = 0; k < 16; k++) {
        a0[k] = ur_w1[3 * k + 0];
        hb[k] = fmaf(fs, ur_w1[3 * k + 1], fmaf(fg, ur_w1[3 * k + 2], ur_b1[k]));
        w2[k] = ur_w2[k];
    }
    float b2 = ur_b2[0];

    int tid = blockIdx.x * blockDim.x + threadIdx.x;
    int stride = gridDim.x * blockDim.x;
    float sabs = 0.f;
    vfloat2 sdv01 = {0.f, 0.f}, sdv23 = {0.f, 0.f};
    int i = tid;
    for (; i + (UNROLL - 1) * stride < n4; i += UNROLL * stride) {
        vfloat4 v[UNROLL], d[UNROLL];
#pragma unroll
        for (int u = 0; u < UNROLL; u++) v[u] = w[i + u * stride];
#pragma unroll
        for (int u = 0; u < UNROLL; u++) d[u] = dw[i + u * stride];
#pragma unroll
        for (int u = 0; u < UNROLL; u++) {
            // ssq_dw, packed (v_pk_fma_f32)
            vfloat2 d01 = {d[u].x, d[u].y}, d23 = {d[u].z, d[u].w};
            sdv01 += d01 * d01;
            sdv23 += d23 * d23;
            // 16-hinge MLP on element pairs: v_pk_fma / v_pk_max.
            vfloat2 x01 = {v[u].x, v[u].y}, x23 = {v[u].z, v[u].w};
            vfloat2 acc01 = {b2, b2}, acc23 = {b2, b2};
#pragma unroll
            for (int k = 0; k < 16; k++) {
                vfloat2 h01 = x01 * a0[k] + hb[k];
                vfloat2 h23 = x23 * a0[k] + hb[k];
                h01 = __builtin_elementwise_max(h01, (vfloat2)0.0f);
                h23 = __builtin_elementwise_max(h23, (vfloat2)0.0f);
                acc01 += h01 * w2[k];
                acc23 += h23 * w2[k];
            }
            float accs[4] = {acc01.x, acc01.y, acc23.x, acc23.y};
            float xs[4] = {v[u].x, v[u].y, v[u].z, v[u].w};
            vfloat4 o;
#pragma unroll
            for (int e = 0; e < 4; e++) {
                float t = __expf(2.0f * accs[e]);
                float th = fmaf(-2.0f, __builtin_amdgcn_rcpf(t + 1.0f), 1.0f);
                float nw = fmaf(0.001f, th, xs[e]);
                nw = fminf(fmaxf(nw, -10.0f), 10.0f);
                o[e] = nw;
                sabs += fabsf(nw);
            }
            outw[i + u * stride] = o;    // plain cacheable store: let L2/L3 defer
        }
    }
    for (; i < n4; i += stride) {     // generic tail (not executed at n=16.7M)
        vfloat4 v = w[i];
        vfloat4 d = dw[i];
        vfloat2 d01 = {d.x, d.y}, d23 = {d.z, d.w};
        sdv01 += d01 * d01;
        sdv23 += d23 * d23;
        vfloat4 o;
#pragma unroll
        for (int e = 0; e < 4; e++) {
            float x = v[e];
            float acc = b2;
#pragma unroll
            for (int k = 0; k < 16; k++) {
                float h = fmaf(x, a0[k], hb[k]);
                acc = fmaf(fmaxf(h, 0.0f), w2[k], acc);
            }
            float t = __expf(2.0f * acc);
            float th = fmaf(-2.0f, __builtin_amdgcn_rcpf(t + 1.0f), 1.0f);
            float nw = fmaf(0.001f, th, x);
            nw = fminf(fmaxf(nw, -10.0f), 10.0f);
            o[e] = nw;
            sabs += fabsf(nw);
        }
        outw[i] = o;
    }
    float sdw = (sdv01.x + sdv01.y) + (sdv23.x + sdv23.y);
    for (int off = 32; off > 0; off >>= 1) {
        sabs += __shfl_down(sabs, off);
        sdw  += __shfl_down(sdw, off);
    }
    __shared__ float lsa[4], lsd[4];
    int wave = threadIdx.x >> 6;
    int lane = threadIdx.x & 63;
    if (lane == 0) { lsa[wave] = sabs; lsd[wave] = sdw; }
    __syncthreads();
    if (threadIdx.x == 0) {
        vfloat2 p;
        p.x = (lsa[0] + lsa[1]) + (lsa[2] + lsa[3]);
        p.y = (lsd[0] + lsd[1]) + (lsd[2] + lsd[3]);
        cd_part[blockIdx.x] = p;   // kernel-boundary handoff to finalize
    }
}

// ---- k4: VERBATIM R0 finalize: fold partials -> change_magnitude, quality ----
__global__ __launch_bounds__(1024) void wc_finalize(const vfloat2* __restrict__ cd_part,
                                                    float* __restrict__ out_tail,
                                                    double inv_n) {
    double sa = 0.0, sd = 0.0;
    for (int i = threadIdx.x; i < NBLK; i += 1024) {
        vfloat2 p = cd_part[i];
        sa += (double)p.x;
        sd += (double)p.y;
    }
    for (int off = 32; off > 0; off >>= 1) {
        sa += __shfl_down(sa, off);
        sd += __shfl_down(sd, off);
    }
    __shared__ double lsa[16], lsd[16];
    int wave = threadIdx.x >> 6;
    int lane = threadIdx.x & 63;
    if (lane == 0) { lsa[wave] = sa; lsd[wave] = sd; }
    __syncthreads();
    if (threadIdx.x == 0) {
        double ta = 0.0, td = 0.0;
        for (int k = 0; k < 16; k++) { ta += lsa[k]; td += lsd[k]; }
        out_tail[1] = sqrtf((float)td);          // change_magnitude
        float mean_abs = (float)(ta * inv_n);
        float dq = (mean_abs > 0.1f && mean_abs < 0.9f) ? 1.0f : mean_abs;
        out_tail[3] = (0.5f + dq) * 0.5f;        // consolidation_quality
    }
}

extern "C" void kernel_launch(void* const* d_in, const int* in_sizes, int n_in,
                              void* d_out, int out_size, void* d_ws, size_t ws_size,
                              hipStream_t stream) {
    const float* cur_w = (const float*)d_in[0];
    const float* w_chg = (const float*)d_in[1];
    const float* ur_w1 = (const float*)d_in[2];
    const float* ur_b1 = (const float*)d_in[3];
    const float* ur_w2 = (const float*)d_in[4];
    const float* ur_b2 = (const float*)d_in[5];
    const float* fg_w1 = (const float*)d_in[6];
    const float* fg_b1 = (const float*)d_in[7];
    const float* fg_w2 = (const float*)d_in[8];
    const float* fg_b2 = (const float*)d_in[9];

    int n = in_sizes[0];          // 16777216 (4096x4096)
    int n4 = n / 4;

    int pn4 = n4 < (1 << 20) ? n4 : (1 << 20);   // 4M-element prefix (1M vfloat4)

    float* w_part = (float*)d_ws;
    vfloat2* cd_part = (vfloat2*)((char*)d_ws + 8192);
    float* wsf = (float*)((char*)d_ws + 24576);

    float* out_w = (float*)d_out;
    float* out_tail = out_w + n;

    // 4 launches; overhead measured launch-count-insensitive (R0/R2/R5/R6: 111-121 us
    // fixed), so structure is chosen purely to keep each kernel at its measured best.
    wc_prefix<<<PBLK, THREADS, 0, stream>>>((const vfloat4*)cur_w, w_part, pn4);

    wc_scalars<<<1, THREADS, 0, stream>>>(w_part, (const vfloat4*)cur_w, wsf,
                                          fg_w1, fg_b1, fg_w2, fg_b2, out_tail, n4);

    wc_consolidate<<<NBLK, THREADS, 0, stream>>>((const vfloat4*)cur_w, (const vfloat4*)w_chg,
                                                 (vfloat4*)out_w, ur_w1, ur_b1, ur_w2, ur_b2,
                                                 wsf, cd_part, n4);

    wc_finalize<<<1, 1024, 0, stream>>>(cd_part, out_tail, 1.0 / (double)n);
}